// Round 4
// baseline (175.285 us; speedup 1.0000x reference)
//
#include <hip/hip_runtime.h>
#include <math.h>

#define IMG   256
#define DETN  362
#define NFULL 177
#define NACQ  45
#define PAD   1024

// ws layout (floats): [0,131072) sino ; [131072,262144) sf
#define SINO_OFF 0
#define SF_OFF   131072

#define LDSF  5632     // floats for the staged tile (22.5 KB)
#define TTILE 32
#define SEG0  64

// ---------------------------------------------------------------------------
// Kernel A: radon with LDS band staging.
// Block = one (b,angle) x 32-detector-bin tile, 256 thr = 32 T x 8 S-phase.
// Per 64-sample S-segment: stage the bbox of the rotated patch into LDS
// (coalesced, zero-filled outside image), then branch-free bilinear from LDS.
__global__ __launch_bounds__(256) void radon_kernel(
    const float* __restrict__ x,       // (2,1,256,256)
    const float* __restrict__ thetas,  // (177)
    float* __restrict__ sino)          // (2,177,362)
{
    const int blk = blockIdx.x;        // b*NFULL + a
    const int b = blk / NFULL;
    const int a = blk - b * NFULL;
    const int T0 = blockIdx.y * TTILE;
    const int tid = threadIdx.x;
    const int ts = tid & 7;            // S phase
    const int tt = tid >> 3;           // T within tile (0..31)
    const int T = T0 + tt;

    __shared__ float tile[LDSF];
    __shared__ int sSlo, sShi;

    const float th = thetas[a] * (float)(M_PI / 180.0);
    const float c = cosf(th);
    const float s = sinf(th);
    const float cx = (IMG - 1) * 0.5f;
    const float cy = (IMG - 1) * 0.5f;
    const float Tc = (float)T - (DETN - 1) * 0.5f;
    const float xbase = Tc * c + cx;   // xs = xbase - sval*s
    const float ybase = Tc * s + cy;   // ys = ybase + sval*c

    // per-thread valid-S clipping (4-tap footprint can touch image)
    float lo = -1e30f, hi = 1e30f;
    bool empty = (T >= DETN);
    {   const float aa = -s;
        if (aa > 1e-5f)       { lo = fmaxf(lo, (-1.0f - xbase) / aa); hi = fminf(hi, (256.0f - xbase) / aa); }
        else if (aa < -1e-5f) { lo = fmaxf(lo, (256.0f - xbase) / aa); hi = fminf(hi, (-1.0f - xbase) / aa); }
        else if (xbase <= -1.0f || xbase >= 256.0f) empty = true;
    }
    {   const float aa = c;
        if (aa > 1e-5f)       { lo = fmaxf(lo, (-1.0f - ybase) / aa); hi = fminf(hi, (256.0f - ybase) / aa); }
        else if (aa < -1e-5f) { lo = fmaxf(lo, (256.0f - ybase) / aa); hi = fminf(hi, (-1.0f - ybase) / aa); }
        else if (ybase <= -1.0f || ybase >= 256.0f) empty = true;
    }
    lo = fmaxf(lo, -200.0f);
    hi = fminf(hi, 200.0f);
    int Slo = max(0, (int)floorf(lo + (DETN - 1) * 0.5f) - 1);
    int Shi = min(DETN, (int)floorf(hi + (DETN - 1) * 0.5f) + 2);
    if (empty || Shi < Slo) { Slo = 0; Shi = 0; }

    // block-level S-range union
    if (tid == 0) { sSlo = DETN; sShi = 0; }
    __syncthreads();
    if (Shi > Slo) { atomicMin(&sSlo, Slo); atomicMax(&sShi, Shi); }
    __syncthreads();
    const int SloB = sSlo, ShiB = sShi;

    const float* __restrict__ img = x + b * IMG * IMG;
    const float TcA = (float)T0 - (DETN - 1) * 0.5f;
    const float TcB = (float)(T0 + TTILE - 1) - (DETN - 1) * 0.5f;
    const int wave = tid >> 6;
    const int lane = tid & 63;

    float val = 0.0f;
    int Sseg = SloB;
    while (Sseg < ShiB) {
        int segLen = SEG0;
        int Send, ix0, iy0, w, h, pitch;
        for (;;) {
            Send = min(Sseg + segLen, ShiB);
            const float sv0 = (float)Sseg - (DETN - 1) * 0.5f;
            const float sv1 = (float)(Send - 1) - (DETN - 1) * 0.5f;
            const float xA0 = TcA * c + cx - sv0 * s, xA1 = TcA * c + cx - sv1 * s;
            const float xB0 = TcB * c + cx - sv0 * s, xB1 = TcB * c + cx - sv1 * s;
            const float yA0 = TcA * s + cy + sv0 * c, yA1 = TcA * s + cy + sv1 * c;
            const float yB0 = TcB * s + cy + sv0 * c, yB1 = TcB * s + cy + sv1 * c;
            const float xmn = fminf(fminf(xA0, xA1), fminf(xB0, xB1));
            const float xmx = fmaxf(fmaxf(xA0, xA1), fmaxf(xB0, xB1));
            const float ymn = fminf(fminf(yA0, yA1), fminf(yB0, yB1));
            const float ymx = fmaxf(fmaxf(yA0, yA1), fmaxf(yB0, yB1));
            ix0 = (int)floorf(xmn) - 1;
            iy0 = (int)floorf(ymn) - 1;
            const int ix1 = (int)floorf(xmx) + 2;
            const int iy1 = (int)floorf(ymx) + 2;
            w = ix1 - ix0 + 1;
            h = iy1 - iy0 + 1;
            pitch = w | 1;
            if (pitch * h <= LDSF || segLen <= 8) break;   // never halves by analysis
            segLen >>= 1;
        }

        // stage bbox into LDS, coalesced, zero-fill outside the image
        for (int r = wave; r < h; r += 4) {
            const int gy = iy0 + r;
            const bool yok = ((unsigned)gy < IMG);
            const float* row = img + gy * IMG;
            const int rbase = r * pitch;
            for (int col = lane; col < w; col += 64) {
                const int gx = ix0 + col;
                float v = 0.0f;
                if (yok && ((unsigned)gx < IMG)) v = row[gx];
                tile[rbase + col] = v;
            }
        }
        __syncthreads();

        // branch-free bilinear sampling from LDS
        const float fx0 = (float)ix0;
        const float fy0 = (float)iy0;
        #pragma unroll 2
        for (int S = Sseg + ts; S < Send; S += 8) {
            const float sval = (float)S - (DETN - 1) * 0.5f;
            const float xs = (xbase - sval * s) - fx0;
            const float ys = (ybase + sval * c) - fy0;
            const float x0f = floorf(xs);
            const float y0f = floorf(ys);
            const float wx = xs - x0f;
            const float wy = ys - y0f;
            const int base = (int)y0f * pitch + (int)x0f;
            const float v00 = tile[base];
            const float v01 = tile[base + 1];
            const float v10 = tile[base + pitch];
            const float v11 = tile[base + pitch + 1];
            val += (v00 * (1.0f - wx) + v01 * wx) * (1.0f - wy)
                 + (v10 * (1.0f - wx) + v11 * wx) * wy;
        }
        __syncthreads();
        Sseg = Send;
    }

    // reduce the 8 S-phase lanes (contiguous lanes, width-8 butterfly)
    val += __shfl_xor(val, 1, 8);
    val += __shfl_xor(val, 2, 8);
    val += __shfl_xor(val, 4, 8);
    if (ts == 0 && T < DETN) {
        sino[(b * NFULL + a) * DETN + T] = val;
    }
}

// ---------------------------------------------------------------------------
// Kernel B: data-consistency + ramp filter (scale pi/(2A) folded in).
// Block 128 thr, 3 outputs/thread: col[m] read amortized over 3 gf reads.
__global__ __launch_bounds__(128) void dc_filter_kernel(
    const float* __restrict__ sino,    // (2,177,362)
    const float* __restrict__ st,      // (2,1,362,45)
    const int*   __restrict__ acq,     // (45)
    float* __restrict__ sf)            // (2,177,362), pre-scaled
{
    const int blk = blockIdx.x;
    const int b = blk / NFULL;
    const int a = blk - b * NFULL;
    const int tid = threadIdx.x;

    __shared__ float col[DETN];
    __shared__ float gf[PAD];

    const double SC = M_PI / (2.0 * NFULL);
    for (int n = tid; n < PAD; n += 128) {
        float v = 0.0f;
        if (n == 0) {
            v = (float)(0.5 * SC);
        } else if (n & 1) {
            int d = (n < PAD - n) ? n : (PAD - n);
            double pd = M_PI * (double)d;
            v = (float)(-2.0 / (pd * pd) * SC);
        }
        gf[n] = v;
    }

    int inv = -1;
    for (int i = 0; i < NACQ; ++i) {
        if (acq[i] == a) inv = i;
    }

    for (int T = tid; T < DETN; T += 128) {
        float val = sino[(b * NFULL + a) * DETN + T];
        if (inv >= 0) {
            val = st[(b * DETN + T) * NACQ + inv] - val;
        }
        col[T] = val;
    }
    __syncthreads();

    const int T1 = tid, T2 = tid + 128, T3 = tid + 256;
    float a1 = 0.0f, a2 = 0.0f, a3 = 0.0f;
    #pragma unroll 4
    for (int m = 0; m < DETN; ++m) {
        const float cm = col[m];
        a1 += cm * gf[(T1 - m) & (PAD - 1)];
        a2 += cm * gf[(T2 - m) & (PAD - 1)];
        a3 += cm * gf[(T3 - m) & (PAD - 1)];
    }
    float* dst = sf + (b * NFULL + a) * DETN;
    dst[T1] = a1;
    dst[T2] = a2;
    if (T3 < DETN) dst[T3] = a3;
}

// ---------------------------------------------------------------------------
// Kernel C: backprojection. grid 2048, block 256 = 64 pixels x 4 angle-phases.
__global__ __launch_bounds__(256) void backproject_kernel(
    const float* __restrict__ sf,      // (2,177,362) pre-scaled
    const float* __restrict__ thetas,  // (177)
    float* __restrict__ out)           // (2,1,256,256)
{
    __shared__ float cs[NFULL];
    __shared__ float sn[NFULL];
    __shared__ float red[256];
    const int tid = threadIdx.x;
    for (int a = tid; a < NFULL; a += 256) {
        float th = thetas[a] * (float)(M_PI / 180.0);
        cs[a] = cosf(th);
        sn[a] = sinf(th);
    }
    __syncthreads();

    const int lane  = tid & 63;
    const int phase = tid >> 6;
    const int pix = blockIdx.x * 64 + lane;          // b*65536 + y*256 + x
    const int b = pix >> 16;
    const int y = (pix >> 8) & 255;
    const int xq = pix & 255;
    const float gx = (float)xq - (IMG - 1) * 0.5f;
    const float gy = (float)y  - (IMG - 1) * 0.5f;
    const float* __restrict__ sfb = sf + b * NFULL * DETN;

    float acc = 0.0f;
    #pragma unroll 4
    for (int a = phase; a < NFULL; a += 4) {
        const float t = cs[a] * gx + sn[a] * gy + (DETN - 1) * 0.5f;
        const float t0f = floorf(t);
        const float w = t - t0f;
        const int t0 = (int)t0f;
        const float* row = sfb + a * DETN;
        const float v0 = ((unsigned)t0 < DETN)       ? row[t0]     : 0.0f;
        const float v1 = ((unsigned)(t0 + 1) < DETN) ? row[t0 + 1] : 0.0f;
        acc += v0 * (1.0f - w) + v1 * w;
    }
    red[tid] = acc;
    __syncthreads();
    if (tid < 64) {
        out[blockIdx.x * 64 + tid] =
            red[tid] + red[tid + 64] + red[tid + 128] + red[tid + 192];
    }
}

extern "C" void kernel_launch(void* const* d_in, const int* in_sizes, int n_in,
                              void* d_out, int out_size, void* d_ws, size_t ws_size,
                              hipStream_t stream) {
    const float* x      = (const float*)d_in[0];   // x_source (2,1,256,256)
    const float* st     = (const float*)d_in[1];   // s_target (2,1,362,45)
    const float* thetas = (const float*)d_in[2];   // thetas_deg (177)
    const int*   acq    = (const int*)d_in[3];     // acq_idx (45)
    float* out  = (float*)d_out;                   // (2,1,256,256) fp32
    float* wsf  = (float*)d_ws;
    float* sino = wsf + SINO_OFF;
    float* sf   = wsf + SF_OFF;

    dim3 gA(2 * NFULL, (DETN + TTILE - 1) / TTILE);   // 354 x 12
    radon_kernel<<<gA, 256, 0, stream>>>(x, thetas, sino);
    dc_filter_kernel<<<2 * NFULL, 128, 0, stream>>>(sino, st, acq, sf);
    backproject_kernel<<<(2 * IMG * IMG) / 64, 256, 0, stream>>>(sf, thetas, out);
}

// Round 5
// 167.320 us; speedup vs baseline: 1.0476x; 1.0476x over previous
//
#include <hip/hip_runtime.h>
#include <math.h>

#define IMG   256
#define DETN  362
#define NFULL 177
#define NACQ  45
#define PAD   1024

// ws layout (floats): [0,131072) sino ; [131072,262144) sf
#define SINO_OFF 0
#define SF_OFF   131072

#define LDSF  5632     // floats for the staged tile (22.5 KB)
#define TTILE 32
#define SEG0  128

// ---------------------------------------------------------------------------
// Kernel A: radon with LDS band staging + deep ILP.
// Block = one (b,angle) x 32-detector-bin tile, 256 thr = 32 T x 8 S-phase.
__global__ __launch_bounds__(256) void radon_kernel(
    const float* __restrict__ x,       // (2,1,256,256)
    const float* __restrict__ thetas,  // (177)
    float* __restrict__ sino)          // (2,177,362)
{
    const int blk = blockIdx.x;        // b*NFULL + a
    const int b = blk / NFULL;
    const int a = blk - b * NFULL;
    const int T0 = blockIdx.y * TTILE;
    const int tid = threadIdx.x;
    const int ts = tid & 7;            // S phase
    const int tt = tid >> 3;           // T within tile (0..31)
    const int T = T0 + tt;

    __shared__ float tile[LDSF];
    __shared__ int sSlo, sShi;

    const float th = thetas[a] * (float)(M_PI / 180.0);
    const float c = cosf(th);
    const float s = sinf(th);
    const float cx = (IMG - 1) * 0.5f;
    const float cy = (IMG - 1) * 0.5f;
    const float Tc = (float)T - (DETN - 1) * 0.5f;
    const float xbase = Tc * c + cx;   // xs = xbase - sval*s
    const float ybase = Tc * s + cy;   // ys = ybase + sval*c

    // per-thread valid-S clipping (4-tap footprint can touch image)
    float lo = -1e30f, hi = 1e30f;
    bool empty = (T >= DETN);
    {   const float aa = -s;
        if (aa > 1e-5f)       { lo = fmaxf(lo, (-1.0f - xbase) / aa); hi = fminf(hi, (256.0f - xbase) / aa); }
        else if (aa < -1e-5f) { lo = fmaxf(lo, (256.0f - xbase) / aa); hi = fminf(hi, (-1.0f - xbase) / aa); }
        else if (xbase <= -1.0f || xbase >= 256.0f) empty = true;
    }
    {   const float aa = c;
        if (aa > 1e-5f)       { lo = fmaxf(lo, (-1.0f - ybase) / aa); hi = fminf(hi, (256.0f - ybase) / aa); }
        else if (aa < -1e-5f) { lo = fmaxf(lo, (256.0f - ybase) / aa); hi = fminf(hi, (-1.0f - ybase) / aa); }
        else if (ybase <= -1.0f || ybase >= 256.0f) empty = true;
    }
    lo = fmaxf(lo, -200.0f);
    hi = fminf(hi, 200.0f);
    int Slo = max(0, (int)floorf(lo + (DETN - 1) * 0.5f) - 1);
    int Shi = min(DETN, (int)floorf(hi + (DETN - 1) * 0.5f) + 2);
    if (empty || Shi < Slo) { Slo = 0; Shi = 0; }

    // block-level S-range union
    if (tid == 0) { sSlo = DETN; sShi = 0; }
    __syncthreads();
    if (Shi > Slo) { atomicMin(&sSlo, Slo); atomicMax(&sShi, Shi); }
    __syncthreads();
    const int SloB = sSlo, ShiB = sShi;

    const float* __restrict__ img = x + b * IMG * IMG;
    const float TcA = (float)T0 - (DETN - 1) * 0.5f;
    const float TcB = (float)(T0 + TTILE - 1) - (DETN - 1) * 0.5f;
    const int wave = tid >> 6;
    const int lane = tid & 63;

    float val = 0.0f;
    int Sseg = SloB;
    while (Sseg < ShiB) {
        int segLen = SEG0;
        int Send, ix0, iy0, w, h, pitch;
        for (;;) {
            Send = min(Sseg + segLen, ShiB);
            const float sv0 = (float)Sseg - (DETN - 1) * 0.5f;
            const float sv1 = (float)(Send - 1) - (DETN - 1) * 0.5f;
            const float xA0 = TcA * c + cx - sv0 * s, xA1 = TcA * c + cx - sv1 * s;
            const float xB0 = TcB * c + cx - sv0 * s, xB1 = TcB * c + cx - sv1 * s;
            const float yA0 = TcA * s + cy + sv0 * c, yA1 = TcA * s + cy + sv1 * c;
            const float yB0 = TcB * s + cy + sv0 * c, yB1 = TcB * s + cy + sv1 * c;
            const float xmn = fminf(fminf(xA0, xA1), fminf(xB0, xB1));
            const float xmx = fmaxf(fmaxf(xA0, xA1), fmaxf(xB0, xB1));
            const float ymn = fminf(fminf(yA0, yA1), fminf(yB0, yB1));
            const float ymx = fmaxf(fmaxf(yA0, yA1), fmaxf(yB0, yB1));
            ix0 = (int)floorf(xmn) - 1;
            iy0 = (int)floorf(ymn) - 1;
            const int ix1 = (int)floorf(xmx) + 2;
            const int iy1 = (int)floorf(ymx) + 2;
            w = ix1 - ix0 + 1;
            h = iy1 - iy0 + 1;
            pitch = w | 1;
            if (pitch * h <= LDSF || segLen <= 8) break;
            segLen >>= 1;
        }

        // stage bbox into LDS, coalesced, zero-fill outside the image
        for (int r = wave; r < h; r += 4) {
            const int gy = iy0 + r;
            const bool yok = ((unsigned)gy < IMG);
            const float* row = img + gy * IMG;
            const int rbase = r * pitch;
            for (int col = lane; col < w; col += 64) {
                const int gx = ix0 + col;
                float v = 0.0f;
                if (yok && ((unsigned)gx < IMG)) v = row[gx];
                tile[rbase + col] = v;
            }
        }
        __syncthreads();

        // per-thread clamp within this segment, 8-phase aligned
        const int Sb = Sseg + ts;
        int Sstart = Sb;
        if (Slo > Sstart) Sstart = Sb + ((((Slo - Sb) + 7) >> 3) << 3);
        const int Sendc = min(Send, Shi);

        // branch-free bilinear from LDS; incremental coords; deep unroll
        float xs = (xbase - ((float)Sstart - (DETN - 1) * 0.5f) * s) - (float)ix0;
        float ys = (ybase + ((float)Sstart - (DETN - 1) * 0.5f) * c) - (float)iy0;
        const float dxs = -8.0f * s;
        const float dys =  8.0f * c;
        #pragma unroll 4
        for (int S = Sstart; S < Sendc; S += 8) {
            const float x0f = floorf(xs);
            const float y0f = floorf(ys);
            const float wx = xs - x0f;
            const float wy = ys - y0f;
            const int base = (int)y0f * pitch + (int)x0f;
            const float v00 = tile[base];
            const float v01 = tile[base + 1];
            const float v10 = tile[base + pitch];
            const float v11 = tile[base + pitch + 1];
            const float h0 = v00 + wx * (v01 - v00);
            const float h1 = v10 + wx * (v11 - v10);
            val += h0 + wy * (h1 - h0);
            xs += dxs;
            ys += dys;
        }
        __syncthreads();
        Sseg = Send;
    }

    // reduce the 8 S-phase lanes
    val += __shfl_xor(val, 1, 8);
    val += __shfl_xor(val, 2, 8);
    val += __shfl_xor(val, 4, 8);
    if (ts == 0 && T < DETN) {
        sino[(b * NFULL + a) * DETN + T] = val;
    }
}

// ---------------------------------------------------------------------------
// Kernel B: data-consistency + ramp filter (scale folded in).
// gf[n]=0 for all even n!=0, so the conv is 181 odd-taps + the center tap.
// grid (354 columns, 2 T-halves), block 192: 1 output/thread.
__global__ __launch_bounds__(192) void dc_filter_kernel(
    const float* __restrict__ sino,    // (2,177,362)
    const float* __restrict__ st,      // (2,1,362,45)
    const int*   __restrict__ acq,     // (45)
    float* __restrict__ sf)            // (2,177,362), pre-scaled
{
    const int blk = blockIdx.x;
    const int b = blk / NFULL;
    const int a = blk - b * NFULL;
    const int tid = threadIdx.x;

    __shared__ float col[DETN];
    __shared__ float gf[PAD];

    const double SC = M_PI / (2.0 * NFULL);
    const float c0 = (float)(0.5 * SC);
    for (int n = tid; n < PAD; n += 192) {
        float v = 0.0f;
        if (n & 1) {
            int d = (n < PAD - n) ? n : (PAD - n);
            double pd = M_PI * (double)d;
            v = (float)(-2.0 / (pd * pd) * SC);
        }
        gf[n] = v;
    }

    int inv = -1;
    for (int i = 0; i < NACQ; ++i) {
        if (acq[i] == a) inv = i;
    }

    for (int m = tid; m < DETN; m += 192) {
        float val = sino[(b * NFULL + a) * DETN + m];
        if (inv >= 0) {
            val = st[(b * DETN + m) * NACQ + inv] - val;
        }
        col[m] = val;
    }
    __syncthreads();

    const int T = blockIdx.y * 181 + tid;     // halves: [0,181) and [181,362)
    if (tid < 181) {
        const int m0 = (T + 1) & 1;           // opposite parity -> odd (T-m)
        float acc = c0 * col[T];
        #pragma unroll 4
        for (int k = 0; k < 181; ++k) {
            const int m = m0 + 2 * k;
            acc += col[m] * gf[(T - m) & (PAD - 1)];
        }
        sf[(b * NFULL + a) * DETN + T] = acc;
    }
}

// ---------------------------------------------------------------------------
// Kernel C: backprojection. grid 2048, block 256 = 64 pixels x 4 angle-phases.
__global__ __launch_bounds__(256) void backproject_kernel(
    const float* __restrict__ sf,      // (2,177,362) pre-scaled
    const float* __restrict__ thetas,  // (177)
    float* __restrict__ out)           // (2,1,256,256)
{
    __shared__ float cs[NFULL];
    __shared__ float sn[NFULL];
    __shared__ float red[256];
    const int tid = threadIdx.x;
    for (int a = tid; a < NFULL; a += 256) {
        float th = thetas[a] * (float)(M_PI / 180.0);
        cs[a] = cosf(th);
        sn[a] = sinf(th);
    }
    __syncthreads();

    const int lane  = tid & 63;
    const int phase = tid >> 6;
    const int pix = blockIdx.x * 64 + lane;          // b*65536 + y*256 + x
    const int b = pix >> 16;
    const int y = (pix >> 8) & 255;
    const int xq = pix & 255;
    const float gx = (float)xq - (IMG - 1) * 0.5f;
    const float gy = (float)y  - (IMG - 1) * 0.5f;
    const float* __restrict__ sfb = sf + b * NFULL * DETN;

    float acc = 0.0f;
    #pragma unroll 4
    for (int a = phase; a < NFULL; a += 4) {
        const float t = cs[a] * gx + sn[a] * gy + (DETN - 1) * 0.5f;
        const float t0f = floorf(t);
        const float w = t - t0f;
        const int t0 = (int)t0f;
        const float* row = sfb + a * DETN;
        const float v0 = ((unsigned)t0 < DETN)       ? row[t0]     : 0.0f;
        const float v1 = ((unsigned)(t0 + 1) < DETN) ? row[t0 + 1] : 0.0f;
        acc += v0 + w * (v1 - v0);
    }
    red[tid] = acc;
    __syncthreads();
    if (tid < 64) {
        out[blockIdx.x * 64 + tid] =
            red[tid] + red[tid + 64] + red[tid + 128] + red[tid + 192];
    }
}

extern "C" void kernel_launch(void* const* d_in, const int* in_sizes, int n_in,
                              void* d_out, int out_size, void* d_ws, size_t ws_size,
                              hipStream_t stream) {
    const float* x      = (const float*)d_in[0];   // x_source (2,1,256,256)
    const float* st     = (const float*)d_in[1];   // s_target (2,1,362,45)
    const float* thetas = (const float*)d_in[2];   // thetas_deg (177)
    const int*   acq    = (const int*)d_in[3];     // acq_idx (45)
    float* out  = (float*)d_out;                   // (2,1,256,256) fp32
    float* wsf  = (float*)d_ws;
    float* sino = wsf + SINO_OFF;
    float* sf   = wsf + SF_OFF;

    dim3 gA(2 * NFULL, (DETN + TTILE - 1) / TTILE);   // 354 x 12
    radon_kernel<<<gA, 256, 0, stream>>>(x, thetas, sino);
    dim3 gB(2 * NFULL, 2);                            // 708 blocks
    dc_filter_kernel<<<gB, 192, 0, stream>>>(sino, st, acq, sf);
    backproject_kernel<<<(2 * IMG * IMG) / 64, 256, 0, stream>>>(sf, thetas, out);
}

// Round 6
// 160.640 us; speedup vs baseline: 1.0912x; 1.0416x over previous
//
#include <hip/hip_runtime.h>
#include <math.h>

#define IMG   256
#define DETN  362
#define NFULL 177
#define NACQ  45
#define PAD   1024

// ws layout (floats): [0,131072) sino ; [131072,262144) sf
#define SINO_OFF 0
#define SF_OFF   131072

#define LDSF  5632     // floats for the staged tile (22.5 KB)
#define TTILE 32
#define SEG   64       // fixed: worst-case AABB (45 deg) = 73x72 = 5256 <= LDSF
#define HALF_T 180.5f  // (DETN-1)/2

// ---------------------------------------------------------------------------
// Kernel A: radon, LDS band staging, fixed 64-sample segments, lean inner loop.
// Block = (b,angle) x 32-T tile, 256 thr = 32 T x 8 S-phase.
__global__ __launch_bounds__(256) void radon_kernel(
    const float* __restrict__ x,       // (2,1,256,256)
    const float* __restrict__ thetas,  // (177)
    float* __restrict__ sino)          // (2,177,362)
{
    const int blk = blockIdx.x;        // b*NFULL + a
    const int b = blk / NFULL;
    const int a = blk - b * NFULL;
    const int T0 = blockIdx.y * TTILE;
    const int tid = threadIdx.x;
    const int ts = tid & 7;            // S phase
    const int tt = tid >> 3;           // T within tile (0..31)
    const int T = T0 + tt;

    __shared__ float tile[LDSF];
    __shared__ int sSlo, sShi;

    const float th = thetas[a] * (float)(M_PI / 180.0);
    const float c = cosf(th);
    const float s = sinf(th);
    const float cx = (IMG - 1) * 0.5f;
    const float cy = (IMG - 1) * 0.5f;
    const float Tc = (float)T - HALF_T;
    const float xbase = Tc * c + cx;   // xs = xbase - sval*s
    const float ybase = Tc * s + cy;   // ys = ybase + sval*c

    // per-thread valid-S clipping (4-tap footprint can touch image)
    float lo = -1e30f, hi = 1e30f;
    bool empty = (T >= DETN);
    {   const float aa = -s;
        if (aa > 1e-5f)       { lo = fmaxf(lo, (-1.0f - xbase) / aa); hi = fminf(hi, (256.0f - xbase) / aa); }
        else if (aa < -1e-5f) { lo = fmaxf(lo, (256.0f - xbase) / aa); hi = fminf(hi, (-1.0f - xbase) / aa); }
        else if (xbase <= -1.0f || xbase >= 256.0f) empty = true;
    }
    {   const float aa = c;
        if (aa > 1e-5f)       { lo = fmaxf(lo, (-1.0f - ybase) / aa); hi = fminf(hi, (256.0f - ybase) / aa); }
        else if (aa < -1e-5f) { lo = fmaxf(lo, (256.0f - ybase) / aa); hi = fminf(hi, (-1.0f - ybase) / aa); }
        else if (ybase <= -1.0f || ybase >= 256.0f) empty = true;
    }
    lo = fmaxf(lo, -200.0f);
    hi = fminf(hi, 200.0f);
    int Slo = max(0, (int)floorf(lo + HALF_T) - 1);
    int Shi = min(DETN, (int)floorf(hi + HALF_T) + 2);
    if (empty || Shi < Slo) { Slo = 0; Shi = 0; }

    // block-level S-range union
    if (tid == 0) { sSlo = DETN; sShi = 0; }
    __syncthreads();
    if (Shi > Slo) { atomicMin(&sSlo, Slo); atomicMax(&sShi, Shi); }
    __syncthreads();
    const int SloB = sSlo, ShiB = sShi;

    const float* __restrict__ img = x + b * IMG * IMG;
    const int wave = tid >> 6;
    const int lane = tid & 63;

    // hoisted tile-corner terms (T extremes of this tile)
    const float TcA = (float)T0 - HALF_T;
    const float TcB = (float)(T0 + TTILE - 1) - HALF_T;
    const float xAB_mn = fminf(TcA * c + cx, TcB * c + cx);
    const float xAB_mx = fmaxf(TcA * c + cx, TcB * c + cx);
    const float yAB_mn = fminf(TcA * s + cy, TcB * s + cy);
    const float yAB_mx = fmaxf(TcA * s + cy, TcB * s + cy);

    float val = 0.0f;
    int Sseg = SloB;
    while (Sseg < ShiB) {
        const int Send = min(Sseg + SEG, ShiB);
        // branch-free AABB for the fixed 64-span (superset for tails)
        const float sv0 = (float)Sseg - HALF_T;
        const float sv1 = sv0 + (float)(SEG - 1);
        const float sx0 = sv0 * s, sx1 = sv1 * s;
        const float cy0 = sv0 * c, cy1 = sv1 * c;
        const float xmn = xAB_mn - fmaxf(sx0, sx1);
        const float xmx = xAB_mx - fminf(sx0, sx1);
        const float ymn = yAB_mn + fminf(cy0, cy1);
        const float ymx = yAB_mx + fmaxf(cy0, cy1);
        const int ix0 = (int)floorf(xmn) - 1;
        const int iy0 = (int)floorf(ymn) - 1;
        const int w = (int)floorf(xmx) + 3 - ix0;
        const int h = (int)floorf(ymx) + 3 - iy0;
        const int pitch = w | 1;

        // stage AABB into LDS, coalesced, zero-fill outside the image
        for (int r = wave; r < h; r += 4) {
            const int gy = iy0 + r;
            const bool yok = ((unsigned)gy < IMG);
            const float* row = img + gy * IMG;
            const int rbase = r * pitch;
            for (int col = lane; col < w; col += 64) {
                const int gx = ix0 + col;
                float v = 0.0f;
                if (yok && ((unsigned)gx < IMG)) v = row[gx];
                tile[rbase + col] = v;
            }
        }
        __syncthreads();

        const float xoff = xbase - (float)ix0;
        const float yoff = ybase - (float)iy0;
        if (Send - Sseg == SEG) {
            // full segment: exactly 8 steps, independent FMA coords
            const float s0 = (float)(Sseg + ts) - HALF_T;
            #pragma unroll 4
            for (int u = 0; u < 8; ++u) {
                const float sval = s0 + (float)(8 * u);
                const float xs = fmaf(-sval, s, xoff);
                const float ys = fmaf(sval, c, yoff);
                const float x0f = floorf(xs);
                const float y0f = floorf(ys);
                const float wx = xs - x0f;
                const float wy = ys - y0f;
                const int base = (int)y0f * pitch + (int)x0f;
                const float v00 = tile[base];
                const float v01 = tile[base + 1];
                const float v10 = tile[base + pitch];
                const float v11 = tile[base + pitch + 1];
                const float h0 = fmaf(wx, v01 - v00, v00);
                const float h1 = fmaf(wx, v11 - v10, v10);
                val += fmaf(wy, h1 - h0, h0);
            }
        } else {
            // tail segment: dynamic count (keeps S < ShiB exact)
            for (int S = Sseg + ts; S < Send; S += 8) {
                const float sval = (float)S - HALF_T;
                const float xs = fmaf(-sval, s, xoff);
                const float ys = fmaf(sval, c, yoff);
                const float x0f = floorf(xs);
                const float y0f = floorf(ys);
                const float wx = xs - x0f;
                const float wy = ys - y0f;
                const int base = (int)y0f * pitch + (int)x0f;
                const float v00 = tile[base];
                const float v01 = tile[base + 1];
                const float v10 = tile[base + pitch];
                const float v11 = tile[base + pitch + 1];
                const float h0 = fmaf(wx, v01 - v00, v00);
                const float h1 = fmaf(wx, v11 - v10, v10);
                val += fmaf(wy, h1 - h0, h0);
            }
        }
        __syncthreads();
        Sseg += SEG;
    }

    // reduce the 8 S-phase lanes
    val += __shfl_xor(val, 1, 8);
    val += __shfl_xor(val, 2, 8);
    val += __shfl_xor(val, 4, 8);
    if (ts == 0 && T < DETN) {
        sino[(b * NFULL + a) * DETN + T] = val;
    }
}

// ---------------------------------------------------------------------------
// Kernel B: data-consistency + ramp filter (scale folded in).
// gf[n]=0 for even n!=0 -> 181 odd taps + center tap.
__global__ __launch_bounds__(192) void dc_filter_kernel(
    const float* __restrict__ sino,    // (2,177,362)
    const float* __restrict__ st,      // (2,1,362,45)
    const int*   __restrict__ acq,     // (45)
    float* __restrict__ sf)            // (2,177,362), pre-scaled
{
    const int blk = blockIdx.x;
    const int b = blk / NFULL;
    const int a = blk - b * NFULL;
    const int tid = threadIdx.x;

    __shared__ float col[DETN];
    __shared__ float gf[PAD];

    const double SC = M_PI / (2.0 * NFULL);
    const float c0 = (float)(0.5 * SC);
    for (int n = tid; n < PAD; n += 192) {
        float v = 0.0f;
        if (n & 1) {
            int d = (n < PAD - n) ? n : (PAD - n);
            double pd = M_PI * (double)d;
            v = (float)(-2.0 / (pd * pd) * SC);
        }
        gf[n] = v;
    }

    int inv = -1;
    for (int i = 0; i < NACQ; ++i) {
        if (acq[i] == a) inv = i;
    }

    for (int m = tid; m < DETN; m += 192) {
        float val = sino[(b * NFULL + a) * DETN + m];
        if (inv >= 0) {
            val = st[(b * DETN + m) * NACQ + inv] - val;
        }
        col[m] = val;
    }
    __syncthreads();

    const int T = blockIdx.y * 181 + tid;     // halves: [0,181) and [181,362)
    if (tid < 181) {
        const int m0 = (T + 1) & 1;           // opposite parity -> odd (T-m)
        float acc = c0 * col[T];
        #pragma unroll 4
        for (int k = 0; k < 181; ++k) {
            const int m = m0 + 2 * k;
            acc += col[m] * gf[(T - m) & (PAD - 1)];
        }
        sf[(b * NFULL + a) * DETN + T] = acc;
    }
}

// ---------------------------------------------------------------------------
// Kernel C: backprojection. grid 2048, block 256 = 64 pixels x 4 angle-phases.
__global__ __launch_bounds__(256) void backproject_kernel(
    const float* __restrict__ sf,      // (2,177,362) pre-scaled
    const float* __restrict__ thetas,  // (177)
    float* __restrict__ out)           // (2,1,256,256)
{
    __shared__ float cs[NFULL];
    __shared__ float sn[NFULL];
    __shared__ float red[256];
    const int tid = threadIdx.x;
    for (int a = tid; a < NFULL; a += 256) {
        float th = thetas[a] * (float)(M_PI / 180.0);
        cs[a] = cosf(th);
        sn[a] = sinf(th);
    }
    __syncthreads();

    const int lane  = tid & 63;
    const int phase = tid >> 6;
    const int pix = blockIdx.x * 64 + lane;          // b*65536 + y*256 + x
    const int b = pix >> 16;
    const int y = (pix >> 8) & 255;
    const int xq = pix & 255;
    const float gx = (float)xq - (IMG - 1) * 0.5f;
    const float gy = (float)y  - (IMG - 1) * 0.5f;
    const float* __restrict__ sfb = sf + b * NFULL * DETN;

    float acc = 0.0f;
    #pragma unroll 4
    for (int a = phase; a < NFULL; a += 4) {
        const float t = cs[a] * gx + sn[a] * gy + HALF_T;
        const float t0f = floorf(t);
        const float w = t - t0f;
        const int t0 = (int)t0f;
        const float* row = sfb + a * DETN;
        const float v0 = ((unsigned)t0 < DETN)       ? row[t0]     : 0.0f;
        const float v1 = ((unsigned)(t0 + 1) < DETN) ? row[t0 + 1] : 0.0f;
        acc += v0 + w * (v1 - v0);
    }
    red[tid] = acc;
    __syncthreads();
    if (tid < 64) {
        out[blockIdx.x * 64 + tid] =
            red[tid] + red[tid + 64] + red[tid + 128] + red[tid + 192];
    }
}

extern "C" void kernel_launch(void* const* d_in, const int* in_sizes, int n_in,
                              void* d_out, int out_size, void* d_ws, size_t ws_size,
                              hipStream_t stream) {
    const float* x      = (const float*)d_in[0];   // x_source (2,1,256,256)
    const float* st     = (const float*)d_in[1];   // s_target (2,1,362,45)
    const float* thetas = (const float*)d_in[2];   // thetas_deg (177)
    const int*   acq    = (const int*)d_in[3];     // acq_idx (45)
    float* out  = (float*)d_out;                   // (2,1,256,256) fp32
    float* wsf  = (float*)d_ws;
    float* sino = wsf + SINO_OFF;
    float* sf   = wsf + SF_OFF;

    dim3 gA(2 * NFULL, (DETN + TTILE - 1) / TTILE);   // 354 x 12
    radon_kernel<<<gA, 256, 0, stream>>>(x, thetas, sino);
    dim3 gB(2 * NFULL, 2);                            // 708 blocks
    dc_filter_kernel<<<gB, 192, 0, stream>>>(sino, st, acq, sf);
    backproject_kernel<<<(2 * IMG * IMG) / 64, 256, 0, stream>>>(sf, thetas, out);
}

// Round 7
// 133.564 us; speedup vs baseline: 1.3124x; 1.2027x over previous
//
#include <hip/hip_runtime.h>
#include <math.h>

#define IMG   256
#define DETN  362
#define NFULL 177
#define NACQ  45
#define PAD   1024

// ws layout (floats):
//   [0,131072)        sino
//   [131072,262144)   sf
//   [262144,811296)   padded images, 2 x 524x524 (origin at image coord -132)
#define SINO_OFF 0
#define SF_OFF   131072
#define PIMG_OFF 262144
#define PW       524
#define PORG     132
#define WS_FAST_BYTES ((size_t)(PIMG_OFF + 2 * PW * PW) * 4)

#define LDSF  6080     // staged-tile floats (24.3 KB) — worst case 80x76
#define TTILE 32
#define SEG   64
#define HALF_T 180.5f  // (DETN-1)/2

// ---------------------------------------------------------------------------
// Kernel P: build zero-framed padded images (exact out-of-image zeros).
__global__ __launch_bounds__(256) void pad_kernel(
    const float* __restrict__ x,       // (2,1,256,256)
    float* __restrict__ pimg)          // (2,524,524)
{
    const int n = 2 * PW * PW;
    for (int i = blockIdx.x * 256 + threadIdx.x; i < n; i += gridDim.x * 256) {
        const int b = i / (PW * PW);
        const int r = i - b * PW * PW;
        const int py = r / PW;
        const int px = r - py * PW;
        const int gx = px - PORG;
        const int gy = py - PORG;
        float v = 0.0f;
        if (((unsigned)gx < IMG) && ((unsigned)gy < IMG))
            v = x[b * IMG * IMG + gy * IMG + gx];
        pimg[i] = v;
    }
}

// ---------------------------------------------------------------------------
// Kernel A (fast): radon from padded image; vectorized, check-free staging.
// Block = (b,angle) x 32-T tile, 256 thr = 32 T x 8 S-phase.
__global__ __launch_bounds__(256) void radon_kernel(
    const float* __restrict__ pimg,    // (2,524,524) padded
    const float* __restrict__ thetas,  // (177)
    float* __restrict__ sino)          // (2,177,362)
{
    const int blk = blockIdx.x;        // b*NFULL + a
    const int b = blk / NFULL;
    const int a = blk - b * NFULL;
    const int T0 = blockIdx.y * TTILE;
    const int tid = threadIdx.x;
    const int ts = tid & 7;            // S phase
    const int tt = tid >> 3;           // T within tile (0..31)
    const int T = T0 + tt;

    __shared__ __align__(16) float tile[LDSF];
    __shared__ int sSlo, sShi;

    const float th = thetas[a] * (float)(M_PI / 180.0);
    const float c = cosf(th);
    const float s = sinf(th);
    const float cx = (IMG - 1) * 0.5f;
    const float cy = (IMG - 1) * 0.5f;
    const float Tc = (float)T - HALF_T;
    const float xbase = Tc * c + cx;   // xs = xbase - sval*s
    const float ybase = Tc * s + cy;   // ys = ybase + sval*c

    // per-thread valid-S clipping (footprint can touch image) -> block union
    float lo = -1e30f, hi = 1e30f;
    bool empty = (T >= DETN);
    {   const float aa = -s;
        if (aa > 1e-5f)       { lo = fmaxf(lo, (-1.0f - xbase) / aa); hi = fminf(hi, (256.0f - xbase) / aa); }
        else if (aa < -1e-5f) { lo = fmaxf(lo, (256.0f - xbase) / aa); hi = fminf(hi, (-1.0f - xbase) / aa); }
        else if (xbase <= -1.0f || xbase >= 256.0f) empty = true;
    }
    {   const float aa = c;
        if (aa > 1e-5f)       { lo = fmaxf(lo, (-1.0f - ybase) / aa); hi = fminf(hi, (256.0f - ybase) / aa); }
        else if (aa < -1e-5f) { lo = fmaxf(lo, (256.0f - ybase) / aa); hi = fminf(hi, (-1.0f - ybase) / aa); }
        else if (ybase <= -1.0f || ybase >= 256.0f) empty = true;
    }
    lo = fmaxf(lo, -200.0f);
    hi = fminf(hi, 200.0f);
    int Slo = max(0, (int)floorf(lo + HALF_T) - 1);
    int Shi = min(DETN, (int)floorf(hi + HALF_T) + 2);
    if (empty || Shi < Slo) { Slo = 0; Shi = 0; }

    if (tid == 0) { sSlo = DETN; sShi = 0; }
    __syncthreads();
    if (Shi > Slo) { atomicMin(&sSlo, Slo); atomicMax(&sShi, Shi); }
    __syncthreads();
    const int SloB = sSlo, ShiB = sShi;

    const float* __restrict__ pb = pimg + b * PW * PW;

    // hoisted tile-corner terms (T extremes of this tile)
    const float TcA = (float)T0 - HALF_T;
    const float TcB = (float)(T0 + TTILE - 1) - HALF_T;
    const float xAB_mn = fminf(TcA * c + cx, TcB * c + cx);
    const float xAB_mx = fmaxf(TcA * c + cx, TcB * c + cx);
    const float yAB_mn = fminf(TcA * s + cy, TcB * s + cy);
    const float yAB_mx = fmaxf(TcA * s + cy, TcB * s + cy);

    float val = 0.0f;
    int Sseg = SloB;
    while (Sseg < ShiB) {
        const int Send = min(Sseg + SEG, ShiB);
        // branch-free AABB for the fixed 64-span (superset for tails)
        const float sv0 = (float)Sseg - HALF_T;
        const float sv1 = sv0 + (float)(SEG - 1);
        const float sx0 = sv0 * s, sx1 = sv1 * s;
        const float cy0 = sv0 * c, cy1 = sv1 * c;
        const float xmn = xAB_mn - fmaxf(sx0, sx1);
        const float xmx = xAB_mx - fminf(sx0, sx1);
        const float ymn = yAB_mn + fminf(cy0, cy1);
        const float ymx = yAB_mx + fmaxf(cy0, cy1);
        const int ix0 = (int)floorf(xmn) - 1;
        const int iy0 = (int)floorf(ymn) - 1;
        const int w = (int)floorf(xmx) + 3 - ix0;
        const int h = (int)floorf(ymx) + 3 - iy0;

        // padded-space window, 16B-aligned left edge
        const int px0  = ix0 + PORG;
        const int py0  = iy0 + PORG;
        const int px0a = px0 & ~3;
        const int wal  = w + (px0 - px0a);
        const int w4   = (wal + 3) >> 2;
        int pitchd = w4 << 2;
        if ((pitchd & 31) == 0) pitchd += 4;     // dodge bank-periodic rows
        const int total4 = w4 * h;
        const unsigned magic = (1u << 22) / (unsigned)w4 + 1;  // exact for n<=1520, d<=20

        // stage: float4 global loads -> float4 LDS writes, no checks
        const float* __restrict__ prow = pb + py0 * PW + px0a;
        for (int f = tid; f < total4; f += 256) {
            const int r  = (int)(((unsigned)f * magic) >> 22);
            const int c4 = f - r * w4;
            const float4 v = *(const float4*)(prow + r * PW + (c4 << 2));
            *(float4*)(tile + r * pitchd + (c4 << 2)) = v;
        }
        __syncthreads();

        const float xoff = xbase + (float)(PORG - px0a);
        const float yoff = ybase - (float)iy0;
        if (Send - Sseg == SEG) {
            const float s0 = (float)(Sseg + ts) - HALF_T;
            #pragma unroll 4
            for (int u = 0; u < 8; ++u) {
                const float sval = s0 + (float)(8 * u);
                const float xs = fmaf(-sval, s, xoff);
                const float ys = fmaf(sval, c, yoff);
                const float x0f = floorf(xs);
                const float y0f = floorf(ys);
                const float wx = xs - x0f;
                const float wy = ys - y0f;
                const int base = (int)y0f * pitchd + (int)x0f;
                const float v00 = tile[base];
                const float v01 = tile[base + 1];
                const float v10 = tile[base + pitchd];
                const float v11 = tile[base + pitchd + 1];
                const float h0 = fmaf(wx, v01 - v00, v00);
                const float h1 = fmaf(wx, v11 - v10, v10);
                val += fmaf(wy, h1 - h0, h0);
            }
        } else {
            for (int S = Sseg + ts; S < Send; S += 8) {
                const float sval = (float)S - HALF_T;
                const float xs = fmaf(-sval, s, xoff);
                const float ys = fmaf(sval, c, yoff);
                const float x0f = floorf(xs);
                const float y0f = floorf(ys);
                const float wx = xs - x0f;
                const float wy = ys - y0f;
                const int base = (int)y0f * pitchd + (int)x0f;
                const float v00 = tile[base];
                const float v01 = tile[base + 1];
                const float v10 = tile[base + pitchd];
                const float v11 = tile[base + pitchd + 1];
                const float h0 = fmaf(wx, v01 - v00, v00);
                const float h1 = fmaf(wx, v11 - v10, v10);
                val += fmaf(wy, h1 - h0, h0);
            }
        }
        __syncthreads();
        Sseg += SEG;
    }

    val += __shfl_xor(val, 1, 8);
    val += __shfl_xor(val, 2, 8);
    val += __shfl_xor(val, 4, 8);
    if (ts == 0 && T < DETN) {
        sino[(b * NFULL + a) * DETN + T] = val;
    }
}

// ---------------------------------------------------------------------------
// Kernel A (fallback, ws too small): R6 radon, bounds-checked staging.
__global__ __launch_bounds__(256) void radon_kernel_fb(
    const float* __restrict__ x,
    const float* __restrict__ thetas,
    float* __restrict__ sino)
{
    const int blk = blockIdx.x;
    const int b = blk / NFULL;
    const int a = blk - b * NFULL;
    const int T0 = blockIdx.y * TTILE;
    const int tid = threadIdx.x;
    const int ts = tid & 7;
    const int tt = tid >> 3;
    const int T = T0 + tt;

    __shared__ float tile[LDSF];
    __shared__ int sSlo, sShi;

    const float th = thetas[a] * (float)(M_PI / 180.0);
    const float c = cosf(th);
    const float s = sinf(th);
    const float cx = (IMG - 1) * 0.5f;
    const float cy = (IMG - 1) * 0.5f;
    const float Tc = (float)T - HALF_T;
    const float xbase = Tc * c + cx;
    const float ybase = Tc * s + cy;

    float lo = -1e30f, hi = 1e30f;
    bool empty = (T >= DETN);
    {   const float aa = -s;
        if (aa > 1e-5f)       { lo = fmaxf(lo, (-1.0f - xbase) / aa); hi = fminf(hi, (256.0f - xbase) / aa); }
        else if (aa < -1e-5f) { lo = fmaxf(lo, (256.0f - xbase) / aa); hi = fminf(hi, (-1.0f - xbase) / aa); }
        else if (xbase <= -1.0f || xbase >= 256.0f) empty = true;
    }
    {   const float aa = c;
        if (aa > 1e-5f)       { lo = fmaxf(lo, (-1.0f - ybase) / aa); hi = fminf(hi, (256.0f - ybase) / aa); }
        else if (aa < -1e-5f) { lo = fmaxf(lo, (256.0f - ybase) / aa); hi = fminf(hi, (-1.0f - ybase) / aa); }
        else if (ybase <= -1.0f || ybase >= 256.0f) empty = true;
    }
    lo = fmaxf(lo, -200.0f);
    hi = fminf(hi, 200.0f);
    int Slo = max(0, (int)floorf(lo + HALF_T) - 1);
    int Shi = min(DETN, (int)floorf(hi + HALF_T) + 2);
    if (empty || Shi < Slo) { Slo = 0; Shi = 0; }

    if (tid == 0) { sSlo = DETN; sShi = 0; }
    __syncthreads();
    if (Shi > Slo) { atomicMin(&sSlo, Slo); atomicMax(&sShi, Shi); }
    __syncthreads();
    const int SloB = sSlo, ShiB = sShi;

    const float* __restrict__ img = x + b * IMG * IMG;
    const int wave = tid >> 6;
    const int lane = tid & 63;

    const float TcA = (float)T0 - HALF_T;
    const float TcB = (float)(T0 + TTILE - 1) - HALF_T;
    const float xAB_mn = fminf(TcA * c + cx, TcB * c + cx);
    const float xAB_mx = fmaxf(TcA * c + cx, TcB * c + cx);
    const float yAB_mn = fminf(TcA * s + cy, TcB * s + cy);
    const float yAB_mx = fmaxf(TcA * s + cy, TcB * s + cy);

    float val = 0.0f;
    int Sseg = SloB;
    while (Sseg < ShiB) {
        const int Send = min(Sseg + SEG, ShiB);
        const float sv0 = (float)Sseg - HALF_T;
        const float sv1 = sv0 + (float)(SEG - 1);
        const float sx0 = sv0 * s, sx1 = sv1 * s;
        const float cy0 = sv0 * c, cy1 = sv1 * c;
        const float xmn = xAB_mn - fmaxf(sx0, sx1);
        const float xmx = xAB_mx - fminf(sx0, sx1);
        const float ymn = yAB_mn + fminf(cy0, cy1);
        const float ymx = yAB_mx + fmaxf(cy0, cy1);
        const int ix0 = (int)floorf(xmn) - 1;
        const int iy0 = (int)floorf(ymn) - 1;
        const int w = (int)floorf(xmx) + 3 - ix0;
        const int h = (int)floorf(ymx) + 3 - iy0;
        const int pitch = w | 1;

        for (int r = wave; r < h; r += 4) {
            const int gy = iy0 + r;
            const bool yok = ((unsigned)gy < IMG);
            const float* row = img + gy * IMG;
            const int rbase = r * pitch;
            for (int col = lane; col < w; col += 64) {
                const int gx = ix0 + col;
                float v = 0.0f;
                if (yok && ((unsigned)gx < IMG)) v = row[gx];
                tile[rbase + col] = v;
            }
        }
        __syncthreads();

        const float xoff = xbase - (float)ix0;
        const float yoff = ybase - (float)iy0;
        for (int S = Sseg + ts; S < Send; S += 8) {
            const float sval = (float)S - HALF_T;
            const float xs = fmaf(-sval, s, xoff);
            const float ys = fmaf(sval, c, yoff);
            const float x0f = floorf(xs);
            const float y0f = floorf(ys);
            const float wx = xs - x0f;
            const float wy = ys - y0f;
            const int base = (int)y0f * pitch + (int)x0f;
            const float v00 = tile[base];
            const float v01 = tile[base + 1];
            const float v10 = tile[base + pitch];
            const float v11 = tile[base + pitch + 1];
            const float h0 = fmaf(wx, v01 - v00, v00);
            const float h1 = fmaf(wx, v11 - v10, v10);
            val += fmaf(wy, h1 - h0, h0);
        }
        __syncthreads();
        Sseg += SEG;
    }

    val += __shfl_xor(val, 1, 8);
    val += __shfl_xor(val, 2, 8);
    val += __shfl_xor(val, 4, 8);
    if (ts == 0 && T < DETN) {
        sino[(b * NFULL + a) * DETN + T] = val;
    }
}

// ---------------------------------------------------------------------------
// Kernel B: data-consistency + ramp filter (scale folded in; odd taps only).
__global__ __launch_bounds__(192) void dc_filter_kernel(
    const float* __restrict__ sino,
    const float* __restrict__ st,
    const int*   __restrict__ acq,
    float* __restrict__ sf)
{
    const int blk = blockIdx.x;
    const int b = blk / NFULL;
    const int a = blk - b * NFULL;
    const int tid = threadIdx.x;

    __shared__ float col[DETN];
    __shared__ float gf[PAD];

    const double SC = M_PI / (2.0 * NFULL);
    const float c0 = (float)(0.5 * SC);
    for (int n = tid; n < PAD; n += 192) {
        float v = 0.0f;
        if (n & 1) {
            int d = (n < PAD - n) ? n : (PAD - n);
            double pd = M_PI * (double)d;
            v = (float)(-2.0 / (pd * pd) * SC);
        }
        gf[n] = v;
    }

    int inv = -1;
    for (int i = 0; i < NACQ; ++i) {
        if (acq[i] == a) inv = i;
    }

    for (int m = tid; m < DETN; m += 192) {
        float val = sino[(b * NFULL + a) * DETN + m];
        if (inv >= 0) {
            val = st[(b * DETN + m) * NACQ + inv] - val;
        }
        col[m] = val;
    }
    __syncthreads();

    const int T = blockIdx.y * 181 + tid;
    if (tid < 181) {
        const int m0 = (T + 1) & 1;
        float acc = c0 * col[T];
        #pragma unroll 4
        for (int k = 0; k < 181; ++k) {
            const int m = m0 + 2 * k;
            acc += col[m] * gf[(T - m) & (PAD - 1)];
        }
        sf[(b * NFULL + a) * DETN + T] = acc;
    }
}

// ---------------------------------------------------------------------------
// Kernel C: backprojection. Block = 64 pixels (same row) x 4 angle-phases.
// t0 in [0,360] always -> range checks removed; {cos, sn*gy+H} packed in LDS.
__global__ __launch_bounds__(256) void backproject_kernel(
    const float* __restrict__ sf,
    const float* __restrict__ thetas,
    float* __restrict__ out)
{
    __shared__ float cb[2 * NFULL];
    __shared__ float red[256];
    const int tid = threadIdx.x;
    const int lane  = tid & 63;
    const int phase = tid >> 6;
    const int pix = blockIdx.x * 64 + lane;          // b*65536 + y*256 + x
    const int b = pix >> 16;
    const int y = (pix >> 8) & 255;
    const int xq = pix & 255;
    const float gx = (float)xq - (IMG - 1) * 0.5f;
    const float gy = (float)y  - (IMG - 1) * 0.5f;   // uniform across block

    for (int a = tid; a < NFULL; a += 256) {
        float th = thetas[a] * (float)(M_PI / 180.0);
        cb[2 * a]     = cosf(th);
        cb[2 * a + 1] = fmaf(sinf(th), gy, HALF_T);
    }
    __syncthreads();

    const float* __restrict__ sfb = sf + b * NFULL * DETN;

    float acc = 0.0f;
    #pragma unroll 4
    for (int a = phase; a < NFULL; a += 4) {
        const float cs = cb[2 * a];
        const float bs = cb[2 * a + 1];
        const float t = fmaf(cs, gx, bs);
        const float t0f = floorf(t);
        const float w = t - t0f;
        const float* row = sfb + a * DETN + (int)t0f;
        const float v0 = row[0];
        const float v1 = row[1];
        acc += v0 + w * (v1 - v0);
    }
    red[tid] = acc;
    __syncthreads();
    if (tid < 64) {
        out[blockIdx.x * 64 + tid] =
            red[tid] + red[tid + 64] + red[tid + 128] + red[tid + 192];
    }
}

extern "C" void kernel_launch(void* const* d_in, const int* in_sizes, int n_in,
                              void* d_out, int out_size, void* d_ws, size_t ws_size,
                              hipStream_t stream) {
    const float* x      = (const float*)d_in[0];
    const float* st     = (const float*)d_in[1];
    const float* thetas = (const float*)d_in[2];
    const int*   acq    = (const int*)d_in[3];
    float* out  = (float*)d_out;
    float* wsf  = (float*)d_ws;
    float* sino = wsf + SINO_OFF;
    float* sf   = wsf + SF_OFF;

    dim3 gA(2 * NFULL, (DETN + TTILE - 1) / TTILE);   // 354 x 12

    if (ws_size >= WS_FAST_BYTES) {
        float* pimg = wsf + PIMG_OFF;
        pad_kernel<<<1024, 256, 0, stream>>>(x, pimg);
        radon_kernel<<<gA, 256, 0, stream>>>(pimg, thetas, sino);
    } else {
        radon_kernel_fb<<<gA, 256, 0, stream>>>(x, thetas, sino);
    }

    dim3 gB(2 * NFULL, 2);                            // 708 blocks
    dc_filter_kernel<<<gB, 192, 0, stream>>>(sino, st, acq, sf);
    backproject_kernel<<<(2 * IMG * IMG) / 64, 256, 0, stream>>>(sf, thetas, out);
}